// Round 5
// baseline (217.344 us; speedup 1.0000x reference)
//
#include <hip/hip_runtime.h>
#include <hip/hip_fp16.h>
#include <hip/hip_cooperative_groups.h>

namespace cg = cooperative_groups;

// CLAHE: B=32, C=3, H=W=512, GRID=8x8 -> TILE=64x64 (4096 px), NUM_BINS=256,
// CLIP_LIMIT=40 -> clip value = 640.
// Fused cooperative kernel: phase1 hist+LUT (all 6144 tiles), grid.sync,
// phase2 bilinear apply (img re-read is L3-resident). luts live in d_ws.

#define NBINS  256
#define TILE   64
#define CH     3
#define HH     512
#define WW     512
#define CLIPV  640
#define PIXELS 4096   // per tile

#define LUTS_FLOATS (32 * 8 * 8 * 3 * NBINS)          // 1,572,864
#define V8_BYTES    ((size_t)32 * 3 * HH * WW)        // 25,165,824
#define GRID_BLKS   768                                // 3 blocks/CU

// ============================ FUSED KERNEL ====================================
__global__ __launch_bounds__(256, 4) void clahe_fused(const float* __restrict__ img,
                                                      float* __restrict__ luts,
                                                      float* __restrict__ out) {
    __shared__ unsigned int hist[NBINS];   // 1 KB
    __shared__ int          scan[NBINS];   // 1 KB
    __shared__ __half2 Tab[2][9][NBINS];   // 18 KB

    const int t   = threadIdx.x;
    const int bid = blockIdx.x;

    // ---------------- Phase 1: 8 tiles per block (6144 / 768) ----------------
    #pragma unroll 1
    for (int it = 0; it < 8; ++it) {
        const int job = bid + it * GRID_BLKS;   // = ((b*8+ty)*8+tx)*3 + c
        int c  = job % 3;
        int r  = job / 3;
        int tx = r % 8;  r /= 8;
        int ty = r % 8;
        int b  = r / 8;

        hist[t] = 0u;
        __syncthreads();

        const float* base = img + ((size_t)(b * CH + c) * HH + (size_t)ty * TILE) * WW + (size_t)tx * TILE;
        #pragma unroll
        for (int j = 0; j < 4; ++j) {
            int f  = t + 256 * j;
            int y  = f >> 4;
            int x4 = f & 15;
            const float4 v = *reinterpret_cast<const float4*>(base + (size_t)y * WW + x4 * 4);
            atomicAdd(&hist[min(max((int)floorf(v.x * 256.0f), 0), 255)], 1u);
            atomicAdd(&hist[min(max((int)floorf(v.y * 256.0f), 0), 255)], 1u);
            atomicAdd(&hist[min(max((int)floorf(v.z * 256.0f), 0), 255)], 1u);
            atomicAdd(&hist[min(max((int)floorf(v.w * 256.0f), 0), 255)], 1u);
        }
        __syncthreads();

        int ci = min((int)hist[t], CLIPV);
        scan[t] = ci;
        __syncthreads();
        for (int off = 1; off < 256; off <<= 1) {
            int add = (t >= off) ? scan[t - off] : 0;
            __syncthreads();
            scan[t] += add;
            __syncthreads();
        }
        int total    = scan[255];
        int excess   = PIXELS - total;
        int residual = excess & 255;
        int redist   = excess >> 8;
        int cum = scan[t] + redist * (t + 1) + min(t + 1, residual);
        float lut = floorf(fminf((float)cum * (255.0f / 4096.0f), 255.0f));
        luts[(size_t)job * NBINS + t] = lut;
        // no trailing barrier needed: scan's 16 barriers order next-iter writes
    }

    __threadfence();            // device-scope release: push luts to shared level
    cg::this_grid().sync();

    // ---------------- Phase 2: 2 bands per block (1536 / 768) ----------------
    #pragma unroll 1
    for (int band = bid; band < 1536; band += GRID_BLKS) {
        __syncthreads();                      // protect Tab from previous readers
        const int g     = band & 15;          // 32-row group
        const int plane = band >> 4;          // b*3 + c
        const int c     = plane % 3;
        const int bb    = plane / 3;
        const int y0    = g * 32;

        int ty0, ty1;
        if (y0 < 32)        { ty0 = 0; ty1 = 0; }
        else if (y0 >= 480) { ty0 = 7; ty1 = 7; }
        else                { ty0 = (y0 - 32) >> 6; ty1 = ty0 + 1; }
        const int rb0 = (bb * 8 + ty0) * 8;
        const int rb1 = (bb * 8 + ty1) * 8;

        float L0[8], L1[8];
        #pragma unroll
        for (int tx = 0; tx < 8; ++tx) {
            L0[tx] = luts[((size_t)((rb0 + tx) * 3 + c)) * NBINS + t];
            L1[tx] = luts[((size_t)((rb1 + tx) * 3 + c)) * NBINS + t];
        }
        constexpr float s = 1.0f / 255.0f;
        #pragma unroll
        for (int tx = 0; tx < 8; ++tx) {
            int txn = (tx < 7) ? tx + 1 : 7;
            Tab[0][tx][t] = __floats2half2_rn(L1[tx] * s, L1[txn] * s);
            Tab[1][tx][t] = __floats2half2_rn((L0[tx] - L1[tx]) * s, (L0[txn] - L1[txn]) * s);
        }
        Tab[0][8][t] = __floats2half2_rn(L1[0] * s, L1[0] * s);
        Tab[1][8][t] = __floats2half2_rn((L0[0] - L1[0]) * s, (L0[0] - L1[0]) * s);
        __syncthreads();

        // thread covers 16 px at x0 (16-aligned: never crosses a blend breakpoint)
        const int x0     = (t & 31) * 16;
        const int tx_sel = (x0 < 32) ? 8 : ((x0 >= 480) ? 7 : ((x0 - 32) >> 6));
        const float c0f  = (float)(63 - ((x0 - 32) & 63));   // garbage at edges; harmless
        const __half2* __restrict__ Arow = &Tab[0][tx_sel][0];
        const __half2* __restrict__ Drow = &Tab[1][tx_sel][0];
        const size_t pb = ((size_t)plane) << 18;

        #pragma unroll
        for (int j = 0; j < 4; ++j) {
            const int row = (t >> 5) + j * 8;
            const int y   = y0 + row;
            const float  wy  = (float)(63 - ((y - 32) & 63)) * (1.0f / 63.0f);
            const __half2 wy2 = __float2half2_rn(wy);
            const size_t p = pb + (size_t)y * WW + x0;

            float pix[16];
            #pragma unroll
            for (int q = 0; q < 4; ++q) {
                float4 f = *reinterpret_cast<const float4*>(img + p + q * 4);
                pix[q * 4 + 0] = f.x; pix[q * 4 + 1] = f.y;
                pix[q * 4 + 2] = f.z; pix[q * 4 + 3] = f.w;
            }
            float res[16];
            #pragma unroll
            for (int i = 0; i < 16; ++i) {
                int vv = min(max((int)floorf(pix[i] * 255.0f), 0), 255);
                const __half2 a = Arow[vv];
                const __half2 d = Drow[vv];
                const __half2 rr = __hfma2(wy2, d, a);
                const float r0 = __low2float(rr);
                const float r1 = __high2float(rr);
                const float wx = (c0f - (float)i) * (1.0f / 63.0f);
                res[i] = fmaf(wx, r0 - r1, r1);
            }
            float4* o = reinterpret_cast<float4*>(out + p);
            o[0] = make_float4(res[0],  res[1],  res[2],  res[3]);
            o[1] = make_float4(res[4],  res[5],  res[6],  res[7]);
            o[2] = make_float4(res[8],  res[9],  res[10], res[11]);
            o[3] = make_float4(res[12], res[13], res[14], res[15]);
        }
    }
}

// ===================== FALLBACK (known-good R4 two-kernel path) ===============
__global__ __launch_bounds__(256) void clahe_hist_lut(const float* __restrict__ img,
                                                      float* __restrict__ luts,
                                                      unsigned char* __restrict__ v8,
                                                      int write_v8) {
    const int bid = blockIdx.x;
    const int t   = threadIdx.x;
    int c  = bid % 3;
    int r  = bid / 3;
    int tx = r % 8;  r /= 8;
    int ty = r % 8;
    int b  = r / 8;

    __shared__ unsigned int hist[NBINS];
    __shared__ int          scan[NBINS];
    hist[t] = 0u;
    __syncthreads();

    const int plane = b * CH + c;
    const float* base = img + ((size_t)plane * HH + (size_t)ty * TILE) * WW + (size_t)tx * TILE;
    unsigned char* v8base = v8 + ((size_t)plane * HH + (size_t)ty * TILE) * WW + (size_t)tx * TILE;

    #pragma unroll
    for (int j = 0; j < 4; ++j) {
        int f  = t + 256 * j;
        int y  = f >> 4;
        int x4 = f & 15;
        const float4 v = *reinterpret_cast<const float4*>(base + (size_t)y * WW + x4 * 4);
        atomicAdd(&hist[min(max((int)floorf(v.x * 256.0f), 0), 255)], 1u);
        atomicAdd(&hist[min(max((int)floorf(v.y * 256.0f), 0), 255)], 1u);
        atomicAdd(&hist[min(max((int)floorf(v.z * 256.0f), 0), 255)], 1u);
        atomicAdd(&hist[min(max((int)floorf(v.w * 256.0f), 0), 255)], 1u);
        if (write_v8) {
            uchar4 q;
            q.x = (unsigned char)min(max((int)floorf(v.x * 255.0f), 0), 255);
            q.y = (unsigned char)min(max((int)floorf(v.y * 255.0f), 0), 255);
            q.z = (unsigned char)min(max((int)floorf(v.z * 255.0f), 0), 255);
            q.w = (unsigned char)min(max((int)floorf(v.w * 255.0f), 0), 255);
            *reinterpret_cast<uchar4*>(v8base + (size_t)y * WW + x4 * 4) = q;
        }
    }
    __syncthreads();

    int ci = min((int)hist[t], CLIPV);
    scan[t] = ci;
    __syncthreads();
    for (int off = 1; off < 256; off <<= 1) {
        int add = (t >= off) ? scan[t - off] : 0;
        __syncthreads();
        scan[t] += add;
        __syncthreads();
    }
    int total    = scan[255];
    int excess   = PIXELS - total;
    int residual = excess & 255;
    int redist   = excess >> 8;
    int cum = scan[t] + redist * (t + 1) + min(t + 1, residual);
    float lut = floorf(fminf((float)cum * (255.0f / 4096.0f), 255.0f));
    luts[(size_t)bid * NBINS + t] = lut;
}

template<bool USE_V8>
__global__ __launch_bounds__(256) void clahe_apply_band(const float* __restrict__ img,
                                                        const unsigned char* __restrict__ v8,
                                                        const float* __restrict__ luts,
                                                        float* __restrict__ out) {
    __shared__ __half2 Tab[2][9][NBINS];

    const int t     = threadIdx.x;
    const int bid   = blockIdx.x;
    const int g     = bid & 15;
    const int plane = bid >> 4;
    const int c     = plane % 3;
    const int bb    = plane / 3;
    const int y0    = g * 32;

    int ty0, ty1;
    if (y0 < 32)        { ty0 = 0; ty1 = 0; }
    else if (y0 >= 480) { ty0 = 7; ty1 = 7; }
    else                { ty0 = (y0 - 32) >> 6; ty1 = ty0 + 1; }

    const int rb0 = (bb * 8 + ty0) * 8;
    const int rb1 = (bb * 8 + ty1) * 8;

    float L0[8], L1[8];
    #pragma unroll
    for (int tx = 0; tx < 8; ++tx) {
        L0[tx] = luts[((size_t)((rb0 + tx) * 3 + c)) * NBINS + t];
        L1[tx] = luts[((size_t)((rb1 + tx) * 3 + c)) * NBINS + t];
    }
    constexpr float s = 1.0f / 255.0f;
    #pragma unroll
    for (int tx = 0; tx < 8; ++tx) {
        int txn = (tx < 7) ? tx + 1 : 7;
        Tab[0][tx][t] = __floats2half2_rn(L1[tx] * s, L1[txn] * s);
        Tab[1][tx][t] = __floats2half2_rn((L0[tx] - L1[tx]) * s, (L0[txn] - L1[txn]) * s);
    }
    Tab[0][8][t] = __floats2half2_rn(L1[0] * s, L1[0] * s);
    Tab[1][8][t] = __floats2half2_rn((L0[0] - L1[0]) * s, (L0[0] - L1[0]) * s);
    __syncthreads();

    const int x0     = (t & 31) * 16;
    const int tx_sel = (x0 < 32) ? 8 : ((x0 >= 480) ? 7 : ((x0 - 32) >> 6));
    const float c0f  = (float)(63 - ((x0 - 32) & 63));
    const __half2* __restrict__ Arow = &Tab[0][tx_sel][0];
    const __half2* __restrict__ Drow = &Tab[1][tx_sel][0];

    const size_t pb = ((size_t)plane) << 18;

    #pragma unroll
    for (int j = 0; j < 4; ++j) {
        const int row = (t >> 5) + j * 8;
        const int y   = y0 + row;
        const float  wy  = (float)(63 - ((y - 32) & 63)) * (1.0f / 63.0f);
        const __half2 wy2 = __float2half2_rn(wy);
        const size_t p = pb + (size_t)y * WW + x0;

        unsigned int w[4];
        float pix[16];
        if constexpr (USE_V8) {
            uint4 raw = *reinterpret_cast<const uint4*>(v8 + p);
            w[0] = raw.x; w[1] = raw.y; w[2] = raw.z; w[3] = raw.w;
        } else {
            #pragma unroll
            for (int q = 0; q < 4; ++q) {
                float4 f = *reinterpret_cast<const float4*>(img + p + q * 4);
                pix[q * 4 + 0] = f.x; pix[q * 4 + 1] = f.y;
                pix[q * 4 + 2] = f.z; pix[q * 4 + 3] = f.w;
            }
        }

        float res[16];
        #pragma unroll
        for (int q = 0; q < 4; ++q) {
            #pragma unroll
            for (int i2 = 0; i2 < 4; ++i2) {
                const int i = q * 4 + i2;
                int vv;
                if constexpr (USE_V8) vv = (w[q] >> (8 * i2)) & 255;
                else                  vv = min(max((int)floorf(pix[i] * 255.0f), 0), 255);
                const __half2 a = Arow[vv];
                const __half2 d = Drow[vv];
                const __half2 rr = __hfma2(wy2, d, a);
                const float r0 = __low2float(rr);
                const float r1 = __high2float(rr);
                const float wx = (c0f - (float)i) * (1.0f / 63.0f);
                res[i] = fmaf(wx, r0 - r1, r1);
            }
        }
        float4* o = reinterpret_cast<float4*>(out + p);
        o[0] = make_float4(res[0],  res[1],  res[2],  res[3]);
        o[1] = make_float4(res[4],  res[5],  res[6],  res[7]);
        o[2] = make_float4(res[8],  res[9],  res[10], res[11]);
        o[3] = make_float4(res[12], res[13], res[14], res[15]);
    }
}

extern "C" void kernel_launch(void* const* d_in, const int* in_sizes, int n_in,
                              void* d_out, int out_size, void* d_ws, size_t ws_size,
                              hipStream_t stream) {
    const float* img  = (const float*)d_in[0];
    float*       out  = (float*)d_out;
    float*       luts = (float*)d_ws;
    unsigned char* v8 = (unsigned char*)d_ws + (size_t)LUTS_FLOATS * 4;

    void* args[] = { (void*)&img, (void*)&luts, (void*)&out };
    hipError_t err = hipLaunchCooperativeKernel((const void*)clahe_fused,
                                                dim3(GRID_BLKS), dim3(256),
                                                args, 0, stream);
    if (err != hipSuccess) {
        // Fallback: known-good two-kernel path (R4)
        const bool use_v8 = ws_size >= (size_t)LUTS_FLOATS * 4 + V8_BYTES;
        clahe_hist_lut<<<32 * 8 * 8 * 3, 256, 0, stream>>>(img, luts, v8, use_v8 ? 1 : 0);
        if (use_v8)
            clahe_apply_band<true><<<1536, 256, 0, stream>>>(img, v8, luts, out);
        else
            clahe_apply_band<false><<<1536, 256, 0, stream>>>(img, v8, luts, out);
    }
}

// Round 6
// 61.648 us; speedup vs baseline: 3.5256x; 3.5256x over previous
//
#include <hip/hip_runtime.h>

// CLAHE: B=32, C=3, H=W=512, GRID=8x8 -> TILE=64x64 (4096 px), NUM_BINS=256,
// CLIP_LIMIT=40 -> clip value = 640.
// d_ws layout: [0, 6.29MB) f32 LUTs (lut_idx = ((b*8+ty)*8+tx)*3 + c),
//              [6.29MB, +25.2MB) u8 quantized image v = clip(floor(img*255)).

#define NBINS  256
#define TILE   64
#define CH     3
#define HH     512
#define WW     512
#define CLIPV  640
#define PIXELS 4096   // per tile

#define LUTS_FLOATS (32 * 8 * 8 * 3 * NBINS)          // 1,572,864
#define V8_BYTES    ((size_t)32 * 3 * HH * WW)        // 25,165,824

// ---------------- Kernel 1: histogram + clip + redistribute + cumsum -> LUT ----
// Also emits the u8 quantized image for the apply pass (write_v8 != 0).
__global__ __launch_bounds__(256) void clahe_hist_lut(const float* __restrict__ img,
                                                      float* __restrict__ luts,
                                                      unsigned char* __restrict__ v8,
                                                      int write_v8) {
    const int bid = blockIdx.x;      // = ((b*8+ty)*8+tx)*3 + c
    const int t   = threadIdx.x;
    int c  = bid % 3;
    int r  = bid / 3;
    int tx = r % 8;  r /= 8;
    int ty = r % 8;
    int b  = r / 8;

    __shared__ unsigned int hist[NBINS];
    __shared__ int          wsum[4];
    hist[t] = 0u;
    __syncthreads();

    const int plane = b * CH + c;
    const float* base = img + ((size_t)plane * HH + (size_t)ty * TILE) * WW + (size_t)tx * TILE;
    unsigned char* v8base = v8 + ((size_t)plane * HH + (size_t)ty * TILE) * WW + (size_t)tx * TILE;

    // 64x64 tile = 1024 float4; 256 threads x 4 iterations, coalesced.
    #pragma unroll
    for (int j = 0; j < 4; ++j) {
        int f  = t + 256 * j;        // float4 index: 64 rows x 16 float4/row
        int y  = f >> 4;
        int x4 = f & 15;
        const float4 v = *reinterpret_cast<const float4*>(base + (size_t)y * WW + x4 * 4);
        atomicAdd(&hist[min(max((int)floorf(v.x * 256.0f), 0), 255)], 1u);
        atomicAdd(&hist[min(max((int)floorf(v.y * 256.0f), 0), 255)], 1u);
        atomicAdd(&hist[min(max((int)floorf(v.z * 256.0f), 0), 255)], 1u);
        atomicAdd(&hist[min(max((int)floorf(v.w * 256.0f), 0), 255)], 1u);
        if (write_v8) {
            uchar4 q;
            q.x = (unsigned char)min(max((int)floorf(v.x * 255.0f), 0), 255);
            q.y = (unsigned char)min(max((int)floorf(v.y * 255.0f), 0), 255);
            q.z = (unsigned char)min(max((int)floorf(v.z * 255.0f), 0), 255);
            q.w = (unsigned char)min(max((int)floorf(v.w * 255.0f), 0), 255);
            *reinterpret_cast<uchar4*>(v8base + (size_t)y * WW + x4 * 4) = q;
        }
    }
    __syncthreads();

    // Clip, then inclusive scan: shfl wave-scan (64 lanes) + 4-wave combine.
    int ci = min((int)hist[t], CLIPV);
    const int lane = t & 63;
    const int wid  = t >> 6;
    int v = ci;
    #pragma unroll
    for (int off = 1; off < 64; off <<= 1) {
        int n = __shfl_up(v, off, 64);
        if (lane >= off) v += n;
    }
    if (lane == 63) wsum[wid] = v;
    __syncthreads();
    int add = 0;
    #pragma unroll
    for (int w = 0; w < 4; ++w) add += (w < wid) ? wsum[w] : 0;
    const int incl  = v + add;                           // inclusive scan at t
    const int total = wsum[0] + wsum[1] + wsum[2] + wsum[3];

    int excess   = PIXELS - total;           // >= 0
    int residual = excess & 255;
    int redist   = excess >> 8;
    // inclusive cumsum of (clipped + redist + (bin<residual ? 1 : 0))
    int cum = incl + redist * (t + 1) + min(t + 1, residual);
    // (nb-1)/pixels = 255/4096 is exact in fp32; cum*scale <= 255 exactly.
    float lut = floorf(fminf((float)cum * (255.0f / 4096.0f), 255.0f));
    luts[(size_t)bid * NBINS + t] = lut;
}

// ---------------- Kernel 2: bilinear LUT application (band-staged, u32 pack) ---
// One block = 32 consecutive rows of one (b,c) plane. All 32-aligned row groups
// lie inside one "band" (rows sharing ty0/ty1: boundaries 32+64k and 480 are
// multiples of 32). Stage ONE u32 per (tx-pair, v):
//   Pack[tx][v] = L1[tx] | L1[tx+1]<<8 | L0[tx]<<16 | L0[tx+1]<<24
// (LUT entries are exact integers 0..255; L0 = L(ty0), L1 = L(ty1).)
// entry 7 duplicates (L7,L7); entry 8 = (L0-col0,L0-col0) serves the left edge,
// so wx needs no edge special-casing (duplicated pairs are wx-invariant).
// Per pixel: 1 ds_read_b32 + ubyte-unpack + 2 lerps. Exact f32 math.
template<bool USE_V8>
__global__ __launch_bounds__(256) void clahe_apply_band(const float* __restrict__ img,
                                                        const unsigned char* __restrict__ v8,
                                                        const float* __restrict__ luts,
                                                        float* __restrict__ out) {
    __shared__ unsigned int Pack[9][NBINS];   // 9 KB

    const int t     = threadIdx.x;
    const int bid   = blockIdx.x;
    const int g     = bid & 15;           // 32-row group 0..15
    const int plane = bid >> 4;           // b*3 + c, 0..95
    const int c     = plane % 3;
    const int bb    = plane / 3;
    const int y0    = g * 32;

    int ty0, ty1;
    if (y0 < 32)        { ty0 = 0; ty1 = 0; }
    else if (y0 >= 480) { ty0 = 7; ty1 = 7; }
    else                { ty0 = (y0 - 32) >> 6; ty1 = ty0 + 1; }

    const int rb0 = (bb * 8 + ty0) * 8;
    const int rb1 = (bb * 8 + ty1) * 8;

    // 16 coalesced 1KB loads (v = t); LUT values are integral 0..255.
    int iL0[8], iL1[8];
    #pragma unroll
    for (int tx = 0; tx < 8; ++tx) {
        iL0[tx] = (int)luts[((size_t)((rb0 + tx) * 3 + c)) * NBINS + t];
        iL1[tx] = (int)luts[((size_t)((rb1 + tx) * 3 + c)) * NBINS + t];
    }
    #pragma unroll
    for (int tx = 0; tx < 8; ++tx) {
        int txn = (tx < 7) ? tx + 1 : 7;
        Pack[tx][t] = (unsigned)(iL1[tx] | (iL1[txn] << 8) | (iL0[tx] << 16) | (iL0[txn] << 24));
    }
    Pack[8][t] = (unsigned)(iL1[0] | (iL1[0] << 8) | (iL0[0] << 16) | (iL0[0] << 24));
    __syncthreads();

    // thread covers 16 px at x0 (16-aligned: never crosses a blend breakpoint)
    const int x0     = (t & 31) * 16;
    const int tx_sel = (x0 < 32) ? 8 : ((x0 >= 480) ? 7 : ((x0 - 32) >> 6));
    const float c0f  = (float)(63 - ((x0 - 32) & 63));   // garbage at edges; harmless
    const unsigned int* __restrict__ Row = &Pack[tx_sel][0];
    const size_t pb = ((size_t)plane) << 18;

    #pragma unroll
    for (int j = 0; j < 4; ++j) {
        const int row = (t >> 5) + j * 8;
        const int y   = y0 + row;
        // On edge bands L0==L1 -> lerp slope 0 -> wy's value is irrelevant.
        const float wy = (float)(63 - ((y - 32) & 63)) * (1.0f / 63.0f);
        const size_t p = pb + (size_t)y * WW + x0;

        unsigned int w[4];
        float pix[16];
        if constexpr (USE_V8) {
            uint4 raw = *reinterpret_cast<const uint4*>(v8 + p);
            w[0] = raw.x; w[1] = raw.y; w[2] = raw.z; w[3] = raw.w;
        } else {
            #pragma unroll
            for (int q = 0; q < 4; ++q) {
                float4 f = *reinterpret_cast<const float4*>(img + p + q * 4);
                pix[q * 4 + 0] = f.x; pix[q * 4 + 1] = f.y;
                pix[q * 4 + 2] = f.z; pix[q * 4 + 3] = f.w;
            }
        }

        float res[16];
        #pragma unroll
        for (int q = 0; q < 4; ++q) {
            #pragma unroll
            for (int i2 = 0; i2 < 4; ++i2) {
                const int i = q * 4 + i2;
                int vv;
                if constexpr (USE_V8) vv = (w[q] >> (8 * i2)) & 255;
                else                  vv = min(max((int)floorf(pix[i] * 255.0f), 0), 255);
                const unsigned int raw = Row[vv];
                const float l1a = (float)(raw & 255u);           // v_cvt_f32_ubyte0
                const float l1b = (float)((raw >> 8) & 255u);    // v_cvt_f32_ubyte1
                const float l0a = (float)((raw >> 16) & 255u);   // v_cvt_f32_ubyte2
                const float l0b = (float)(raw >> 24);            // v_cvt_f32_ubyte3
                const float r0 = fmaf(wy, l0a - l1a, l1a);       // col tx0 value
                const float r1 = fmaf(wy, l0b - l1b, l1b);       // col tx1 value
                const float wx = (c0f - (float)i) * (1.0f / 63.0f);
                res[i] = fmaf(wx, r0 - r1, r1) * (1.0f / 255.0f);
            }
        }
        float4* o = reinterpret_cast<float4*>(out + p);
        o[0] = make_float4(res[0],  res[1],  res[2],  res[3]);
        o[1] = make_float4(res[4],  res[5],  res[6],  res[7]);
        o[2] = make_float4(res[8],  res[9],  res[10], res[11]);
        o[3] = make_float4(res[12], res[13], res[14], res[15]);
    }
}

extern "C" void kernel_launch(void* const* d_in, const int* in_sizes, int n_in,
                              void* d_out, int out_size, void* d_ws, size_t ws_size,
                              hipStream_t stream) {
    const float* img  = (const float*)d_in[0];
    float*       out  = (float*)d_out;
    float*       luts = (float*)d_ws;
    unsigned char* v8 = (unsigned char*)d_ws + (size_t)LUTS_FLOATS * 4;

    const bool use_v8 = ws_size >= (size_t)LUTS_FLOATS * 4 + V8_BYTES;

    // Kernel 1: one block per (b,ty,tx,c)
    clahe_hist_lut<<<32 * 8 * 8 * 3, 256, 0, stream>>>(img, luts, v8, use_v8 ? 1 : 0);
    // Kernel 2: one block per (plane, 32-row band group): 96 * 16 = 1536 blocks
    if (use_v8)
        clahe_apply_band<true><<<1536, 256, 0, stream>>>(img, v8, luts, out);
    else
        clahe_apply_band<false><<<1536, 256, 0, stream>>>(img, v8, luts, out);
}